// Round 8
// baseline (1558.220 us; speedup 1.0000x reference)
//
#include <hip/hip_runtime.h>

typedef unsigned short u16;
typedef __attribute__((ext_vector_type(8))) short bf16x8;
typedef __attribute__((ext_vector_type(4))) float f32x4;
typedef __attribute__((ext_vector_type(4))) u16 u16x4;
typedef __attribute__((ext_vector_type(2))) u16 u16x2;

#define T_TOK 16384
#define D_DIM 1024
#define NE 8
#define MAXP 33792   // max padded compact rows: 2*T + 8*128

__device__ __forceinline__ u16 f2bf(float f) {
  union { float f; unsigned int u; } c; c.f = f;
  unsigned int u = c.u;
  u += 0x7fffu + ((u >> 16) & 1u);   // round-to-nearest-even
  return (u16)(u >> 16);
}

__device__ __forceinline__ float bf2f(u16 v) {
  union { unsigned int u; float f; } c; c.u = ((unsigned int)v) << 16;
  return c.f;
}

__device__ __forceinline__ float gelu_exact(float u) {
  return 0.5f * u * (1.0f + erff(u * 0.70710678118654752f));
}

__device__ __forceinline__ void gld16(const void* g, void* l) {
  __builtin_amdgcn_global_load_lds(
      (const __attribute__((address_space(1))) unsigned int*)g,
      (__attribute__((address_space(3))) unsigned int*)l, 16, 0, 0);
}

// Stage a 128-row x 64-col bf16 tile (contiguous rows) into linear LDS [128][64].
__device__ __forceinline__ void stage_tile(u16* lds, const char* g0, size_t stride,
                                           int wid, int lane) {
  const char* g = g0 + (size_t)(wid * 8 + (lane >> 3)) * stride + (size_t)((lane & 7) * 16);
  char* l = (char*)lds + wid * 1024;   // wave-uniform LDS base; HW adds lane*16
  #pragma unroll
  for (int c = 0; c < 4; ++c)
    gld16(g + (size_t)(32 * c) * stride, l + c * 4096);
}

// One BK=64 step: 32 MFMA per wave, acc[4][4] (64x64 per wave, 2x2 waves = 128x128)
__device__ __forceinline__ void mma_step(const u16* As, const u16* Bs, f32x4 acc[4][4],
                                         int wm, int wn, int lane) {
  const int r = lane & 15, kq = (lane >> 4) * 8;
  #pragma unroll
  for (int ks = 0; ks < 2; ++ks) {
    const int col = ks * 32 + kq;
    bf16x8 a[4], b[4];
    #pragma unroll
    for (int mf = 0; mf < 4; ++mf)
      a[mf] = *(const bf16x8*)&As[(wm * 64 + mf * 16 + r) * 64 + col];
    #pragma unroll
    for (int nf = 0; nf < 4; ++nf)
      b[nf] = *(const bf16x8*)&Bs[(wn * 64 + nf * 16 + r) * 64 + col];
    #pragma unroll
    for (int mf = 0; mf < 4; ++mf)
      #pragma unroll
      for (int nf = 0; nf < 4; ++nf)
        acc[mf][nf] = __builtin_amdgcn_mfma_f32_16x16x32_bf16(a[mf], b[nf], acc[mf][nf], 0, 0, 0);
  }
}

// ---------------- tiled transpose+convert: in[e][R][C] f32 -> out[e][C][R] bf16 ----------------
__global__ __launch_bounds__(256) void transpose_cvt_kernel(const float* __restrict__ in,
                                                            u16* __restrict__ out,
                                                            int R, int C) {
  __shared__ u16 t[32][36];
  const int e = blockIdx.z;
  const int r0 = blockIdx.x * 32, c0 = blockIdx.y * 32;
  const int tid = threadIdx.x;
  {
    const int r = tid >> 3, cq = (tid & 7) * 4;
    float4 v = *(const float4*)(in + ((size_t)e * R + r0 + r) * C + c0 + cq);
    t[r][cq + 0] = f2bf(v.x); t[r][cq + 1] = f2bf(v.y);
    t[r][cq + 2] = f2bf(v.z); t[r][cq + 3] = f2bf(v.w);
  }
  __syncthreads();
  {
    const int c = tid >> 3, rq = (tid & 7) * 4;
    u16x4 o;
    o.x = t[rq + 0][c]; o.y = t[rq + 1][c]; o.z = t[rq + 2][c]; o.w = t[rq + 3][c];
    *(u16x4*)(out + ((size_t)e * C + c0 + c) * R + r0 + rq) = o;
  }
}

// ---------------- gating phase 1: partial GEMM1 over a K-quarter ----------------
// grid (256, 4): blockIdx.x = token block (64 tokens), blockIdx.y = K-quarter (256 K).
// 256 threads, BN=256 (full), BK=8 double-buffered. Thread (tm=tid>>5 in 0..7, tn=tid&31):
// 8 tokens (tm*8..+7) x 8 cols ({tn*4+j, 128+tn*4+j}) -> 64 FMA per 4 ds_read_b128
// (A-reads are 2-address wave-broadcast). Writes fp32 partials + its K-quarter of xb.
__global__ __launch_bounds__(256, 4) void gating_p1_kernel(
    const float* __restrict__ x, const float* __restrict__ wg1,
    u16* __restrict__ xb, float* __restrict__ p_buf) {
  __shared__ float As[2][8][68];    // transposed x chunk [k][m], pad 68 keeps 16B align
  __shared__ float Bs[2][8 * 256];  // wg1 chunk [k][n], linear for global_load_lds
  const int tid = threadIdx.x;
  const int lane = tid & 63, w = tid >> 6;
  const int tn = tid & 31, tm = tid >> 5;
  const int t0 = blockIdx.x * 64;
  const int kq = blockIdx.y;
  const int kbeg = kq * 256;
  const int srow = tid >> 2, sc2 = (tid & 3) * 2;   // 64 rows x (4 thr x 2 k)

  float acc[8][8];
  #pragma unroll
  for (int i = 0; i < 8; ++i)
    #pragma unroll
    for (int j = 0; j < 8; ++j) acc[i][j] = 0.f;

  // ---- prologue: stage first tile into buffer 0 ----
  {
    const char* g = (const char*)wg1 + (size_t)(kbeg + w * 2) * 1024 + lane * 16;
    char* l = (char*)&Bs[0][0] + w * 2048;
    gld16(g, l);
    gld16(g + 1024, l + 1024);
  }
  {
    const float* src = x + (size_t)(t0 + srow) * 1024 + kbeg + sc2;
    float2 v = *(const float2*)src;
    As[0][sc2 + 0][srow] = v.x; As[0][sc2 + 1][srow] = v.y;
    u16x2 o; o.x = f2bf(v.x); o.y = f2bf(v.y);
    *(u16x2*)(xb + (size_t)(t0 + srow) * 1024 + kbeg + sc2) = o;
  }
  __syncthreads();

  int cur = 0;
  for (int k0 = kbeg; k0 < kbeg + 256; k0 += 8) {
    const bool has_next = (k0 + 8) < kbeg + 256;
    float2 xv;
    if (has_next) {
      const char* g = (const char*)wg1 + (size_t)(k0 + 8 + w * 2) * 1024 + lane * 16;
      char* l = (char*)&Bs[cur ^ 1][0] + w * 2048;
      gld16(g, l);
      gld16(g + 1024, l + 1024);
      xv = *(const float2*)(x + (size_t)(t0 + srow) * 1024 + k0 + 8 + sc2);
    }
    #pragma unroll
    for (int kk = 0; kk < 8; ++kk) {
      float4 a0 = *(const float4*)&As[cur][kk][tm * 8];
      float4 a1 = *(const float4*)&As[cur][kk][tm * 8 + 4];
      float4 b0 = *(const float4*)&Bs[cur][kk * 256 + tn * 4];
      float4 b1 = *(const float4*)&Bs[cur][kk * 256 + 128 + tn * 4];
      float av[8] = {a0.x, a0.y, a0.z, a0.w, a1.x, a1.y, a1.z, a1.w};
      float bv[8] = {b0.x, b0.y, b0.z, b0.w, b1.x, b1.y, b1.z, b1.w};
      #pragma unroll
      for (int i = 0; i < 8; ++i)
        #pragma unroll
        for (int j = 0; j < 8; ++j) acc[i][j] += av[i] * bv[j];
    }
    if (has_next) {
      As[cur ^ 1][sc2 + 0][srow] = xv.x; As[cur ^ 1][sc2 + 1][srow] = xv.y;
      u16x2 o; o.x = f2bf(xv.x); o.y = f2bf(xv.y);
      *(u16x2*)(xb + (size_t)(t0 + srow) * 1024 + k0 + 8 + sc2) = o;
    }
    __syncthreads();
    cur ^= 1;
  }

  // store partials: p_buf[kq][t][col], coalesced float4
  #pragma unroll
  for (int i = 0; i < 8; ++i) {
    const size_t t = t0 + tm * 8 + i;
    float* p = &p_buf[((size_t)kq * T_TOK + t) * 256];
    *(float4*)&p[tn * 4]       = make_float4(acc[i][0], acc[i][1], acc[i][2], acc[i][3]);
    *(float4*)&p[128 + tn * 4] = make_float4(acc[i][4], acc[i][5], acc[i][6], acc[i][7]);
  }
}

// ---------------- gating phase 2: combine 4 partials + gelu + GEMM2 + softmax + top2 ----------------
__global__ __launch_bounds__(256) void gating_p2_kernel(
    const float* __restrict__ p_buf, const float* __restrict__ bg1,
    const float* __restrict__ wg2, const float* __restrict__ bg2,
    int* __restrict__ top_i, float2* __restrict__ top_g) {
  const int tid = threadIdx.x;
  const int tn = tid & 31, tm = tid >> 5;
  const int t0 = blockIdx.x * 32;

  float bb[8];
  {
    float4 ba = *(const float4*)&bg1[tn * 4];
    float4 bc = *(const float4*)&bg1[128 + tn * 4];
    bb[0] = ba.x; bb[1] = ba.y; bb[2] = ba.z; bb[3] = ba.w;
    bb[4] = bc.x; bb[5] = bc.y; bb[6] = bc.z; bb[7] = bc.w;
  }

  // h values for this thread's 4 tokens x 8 cols
  float hv[4][8];
  #pragma unroll
  for (int i = 0; i < 4; ++i) {
    const size_t t = t0 + tm * 4 + i;
    float s[8];
    #pragma unroll
    for (int j = 0; j < 8; ++j) s[j] = 0.f;
    #pragma unroll
    for (int q = 0; q < 4; ++q) {
      const float* p = &p_buf[((size_t)q * T_TOK + t) * 256];
      float4 a0 = *(const float4*)&p[tn * 4];
      float4 a1 = *(const float4*)&p[128 + tn * 4];
      s[0] += a0.x; s[1] += a0.y; s[2] += a0.z; s[3] += a0.w;
      s[4] += a1.x; s[5] += a1.y; s[6] += a1.z; s[7] += a1.w;
    }
    #pragma unroll
    for (int j = 0; j < 8; ++j) hv[i][j] = gelu_exact(s[j] + bb[j]);
  }

  float part[4][8];
  #pragma unroll
  for (int i = 0; i < 4; ++i)
    #pragma unroll
    for (int e = 0; e < 8; ++e) part[i][e] = 0.f;
  #pragma unroll
  for (int j = 0; j < 8; ++j) {
    const int col = (j < 4) ? (tn * 4 + j) : (128 + tn * 4 + (j - 4));
    float4 wa = *(const float4*)&wg2[col * 8];
    float4 wb = *(const float4*)&wg2[col * 8 + 4];
    float we[8] = {wa.x, wa.y, wa.z, wa.w, wb.x, wb.y, wb.z, wb.w};
    #pragma unroll
    for (int i = 0; i < 4; ++i)
      #pragma unroll
      for (int e = 0; e < 8; ++e) part[i][e] += hv[i][j] * we[e];
  }
  #pragma unroll
  for (int mask = 1; mask < 32; mask <<= 1)
    #pragma unroll
    for (int i = 0; i < 4; ++i)
      #pragma unroll
      for (int e = 0; e < 8; ++e) part[i][e] += __shfl_xor(part[i][e], mask);

  if (tn < 4) {
    float lg[8];
    #pragma unroll
    for (int i = 0; i < 4; ++i)
      if (tn == i) {
        #pragma unroll
        for (int e = 0; e < 8; ++e) lg[e] = part[i][e];
      }
    #pragma unroll
    for (int e = 0; e < 8; ++e) lg[e] += bg2[e];
    float m = lg[0];
    #pragma unroll
    for (int e = 1; e < 8; ++e) m = fmaxf(m, lg[e]);
    float ex[8], s = 0.f;
    #pragma unroll
    for (int e = 0; e < 8; ++e) { ex[e] = expf(lg[e] - m); s += ex[e]; }
    int i1 = 0;
    #pragma unroll
    for (int e = 1; e < 8; ++e) if (lg[e] > lg[i1]) i1 = e;   // strict >: lowest idx on tie
    int i2 = (i1 == 0) ? 1 : 0;
    #pragma unroll
    for (int e = 0; e < 8; ++e) if (e != i1 && lg[e] > lg[i2]) i2 = e;
    float inv = 1.f / s;
    const int t = t0 + tm * 4 + tn;
    top_i[t] = i1 | (i2 << 8);
    top_g[t] = make_float2(ex[i1] * inv, ex[i2] * inv);
  }
}

// ---------------- hist: per-256-token-chunk expert histogram (LDS atomics only) ----------------
__global__ __launch_bounds__(256) void hist_kernel(const int* __restrict__ top_i,
                                                   int* __restrict__ hist) {
  __shared__ int h[NE];
  const int tid = threadIdx.x;
  if (tid < NE) h[tid] = 0;
  __syncthreads();
  const int ti = top_i[blockIdx.x * 256 + tid];
  atomicAdd(&h[ti & 255], 1);
  atomicAdd(&h[ti >> 8], 1);
  __syncthreads();
  if (tid < NE) hist[blockIdx.x * NE + tid] = h[tid];
}

// ---------------- scan: totals, padded offsets, per-chunk bases (single block) ----------------
__global__ __launch_bounds__(64) void scan_kernel(const int* __restrict__ hist,
                                                  int* __restrict__ cnt,
                                                  int* __restrict__ offs,
                                                  int* __restrict__ cbase) {
  __shared__ int tot[NE], off_s[NE];
  const int tid = threadIdx.x;
  if (tid < NE) {
    int s = 0;
    for (int c = 0; c < 64; ++c) s += hist[c * NE + tid];
    tot[tid] = s; cnt[tid] = s;
  }
  __syncthreads();
  if (tid == 0) {
    int o = 0;
    #pragma unroll
    for (int e = 0; e < NE; ++e) { off_s[e] = o; o += (tot[e] + 127) & ~127; }
  }
  __syncthreads();
  if (tid < NE) {
    offs[tid] = off_s[tid];
    int r = off_s[tid];
    for (int c = 0; c < 64; ++c) { cbase[c * NE + tid] = r; r += hist[c * NE + tid]; }
  }
}

// ---------------- fill: scatter tokens into per-expert compact lists (LDS atomics) ----------------
__global__ __launch_bounds__(256) void fill_kernel(
    const int* __restrict__ top_i, const int* __restrict__ cbase,
    int* __restrict__ tok_list, int* __restrict__ pos1, int* __restrict__ pos2) {
  __shared__ int lcnt[NE];
  const int tid = threadIdx.x;
  if (tid < NE) lcnt[tid] = 0;
  __syncthreads();
  const int t = blockIdx.x * 256 + tid;
  const int ti = top_i[t];
  const int i1 = ti & 255, i2 = ti >> 8;
  const int r1 = atomicAdd(&lcnt[i1], 1);
  const int r2 = atomicAdd(&lcnt[i2], 1);
  const int p1 = cbase[blockIdx.x * NE + i1] + r1;
  const int p2 = cbase[blockIdx.x * NE + i2] + r2;
  tok_list[p1] = t; tok_list[p2] = t;
  pos1[t] = p1; pos2[t] = p2;
}

// ---------------- pass A (compact): h[p][h] = gelu(x[tok[p]] @ W1e + b1e), bf16 ----------------
__global__ __launch_bounds__(256) void expert_h_kernel(
    const u16* __restrict__ xb, const u16* __restrict__ w1t,
    const float* __restrict__ b1, const int* __restrict__ tok_list,
    const int* __restrict__ cnt, const int* __restrict__ offs,
    u16* __restrict__ h_c) {
  __shared__ u16 As[128 * 64];
  __shared__ u16 Bs[128 * 64];
  __shared__ float b1_s[128];
  const int e = blockIdx.z;
  const int nblk = (cnt[e] + 127) >> 7;
  if ((int)blockIdx.x >= nblk) return;
  const int tid = threadIdx.x, lane = tid & 63, wid = tid >> 6;
  const int base = offs[e] + blockIdx.x * 128;
  const int n0 = blockIdx.y * 128;
  const int wm = wid >> 1, wn = wid & 1;

  if (tid < 128) b1_s[tid] = b1[e * 256 + n0 + tid];

  // token ids for this wave's staged rows (hoisted out of the K loop)
  int tk[4];
  {
    const int r0 = wid * 8 + (lane >> 3);
    #pragma unroll
    for (int c = 0; c < 4; ++c) tk[c] = tok_list[base + r0 + 32 * c];
  }

  f32x4 acc[4][4];
  #pragma unroll
  for (int i = 0; i < 4; ++i)
    #pragma unroll
    for (int j = 0; j < 4; ++j) acc[i][j] = (f32x4){0.f, 0.f, 0.f, 0.f};

  const char* Bb = (const char*)w1t + ((size_t)e * 256 + n0) * 2048;
  const int cb = (lane & 7) * 16;
  for (int kt = 0; kt < 16; ++kt) {
    __syncthreads();
    {   // gather-stage A: per-lane global row = tok_list row
      char* l = (char*)As + wid * 1024;
      #pragma unroll
      for (int c = 0; c < 4; ++c)
        gld16((const char*)xb + (size_t)tk[c] * 2048 + kt * 128 + cb, l + c * 4096);
    }
    stage_tile(Bs, Bb + kt * 128, 2048, wid, lane);
    __syncthreads();
    mma_step(As, Bs, acc, wm, wn, lane);
  }

  #pragma unroll
  for (int mf = 0; mf < 4; ++mf)
    #pragma unroll
    for (int rr = 0; rr < 4; ++rr) {
      const int lt = wm * 64 + mf * 16 + ((lane >> 4) << 2) + rr;
      #pragma unroll
      for (int nf = 0; nf < 4; ++nf) {
        const int ln = wn * 64 + nf * 16 + (lane & 15);
        float u = acc[mf][nf][rr] + b1_s[ln];
        h_c[(size_t)(base + lt) * 256 + n0 + ln] = f2bf(gelu_exact(u));
      }
    }
}

// ---------------- pass B (compact): o[p][d] = h[p] @ W2e + b2e, bf16 ----------------
__global__ __launch_bounds__(256) void moe_out_kernel(
    const u16* __restrict__ h_c, const u16* __restrict__ w2t,
    const float* __restrict__ b2, const int* __restrict__ cnt,
    const int* __restrict__ offs, u16* __restrict__ o_c) {
  __shared__ u16 As[128 * 64];
  __shared__ u16 Bs[128 * 64];
  __shared__ float b2_s[128];
  const int e = blockIdx.z;
  const int nblk = (cnt[e] + 127) >> 7;
  if ((int)blockIdx.x >= nblk) return;
  const int tid = threadIdx.x, lane = tid & 63, wid = tid >> 6;
  const int base = offs[e] + blockIdx.x * 128;
  const int n0 = blockIdx.y * 128;
  const int wm = wid >> 1, wn = wid & 1;

  if (tid < 128) b2_s[tid] = b2[(size_t)e * 1024 + n0 + tid];

  f32x4 acc[4][4];
  #pragma unroll
  for (int i = 0; i < 4; ++i)
    #pragma unroll
    for (int j = 0; j < 4; ++j) acc[i][j] = (f32x4){0.f, 0.f, 0.f, 0.f};

  const char* Ab = (const char*)h_c + (size_t)base * 512;
  const char* Bb = (const char*)w2t + ((size_t)e * D_DIM + n0) * 512;
  #pragma unroll 1
  for (int kt = 0; kt < 4; ++kt) {
    __syncthreads();
    stage_tile(As, Ab + kt * 128, 512, wid, lane);
    stage_tile(Bs, Bb + kt * 128, 512, wid, lane);
    __syncthreads();
    mma_step(As, Bs, acc, wm, wn, lane);
  }

  #pragma unroll
  for (int mf = 0; mf < 4; ++mf)
    #pragma unroll
    for (int rr = 0; rr < 4; ++rr) {
      const int lt = wm * 64 + mf * 16 + ((lane >> 4) << 2) + rr;
      #pragma unroll
      for (int nf = 0; nf < 4; ++nf) {
        const int ln = wn * 64 + nf * 16 + (lane & 15);
        o_c[(size_t)(base + lt) * 1024 + n0 + ln] = f2bf(acc[mf][nf][rr] + b2_s[ln]);
      }
    }
}

// ---------------- gather: y[t] = g1*o[p1] + g2*o[p2] ----------------
__global__ __launch_bounds__(256) void gather_kernel(
    const u16* __restrict__ o_c, const int* __restrict__ pos1,
    const int* __restrict__ pos2, const float2* __restrict__ top_g,
    float* __restrict__ y) {
  const int t = blockIdx.x;
  const int p1 = pos1[t], p2 = pos2[t];
  const float2 g = top_g[t];
  const int c = threadIdx.x * 4;
  u16x4 a = *(const u16x4*)&o_c[(size_t)p1 * 1024 + c];
  u16x4 b = *(const u16x4*)&o_c[(size_t)p2 * 1024 + c];
  float4 o;
  o.x = g.x * bf2f(a.x) + g.y * bf2f(b.x);
  o.y = g.x * bf2f(a.y) + g.y * bf2f(b.y);
  o.z = g.x * bf2f(a.z) + g.y * bf2f(b.z);
  o.w = g.x * bf2f(a.w) + g.y * bf2f(b.w);
  *(float4*)&y[(size_t)t * 1024 + c] = o;
}

extern "C" void kernel_launch(void* const* d_in, const int* in_sizes, int n_in,
                              void* d_out, int out_size, void* d_ws, size_t ws_size,
                              hipStream_t stream) {
  (void)in_sizes; (void)n_in; (void)out_size; (void)ws_size;
  const float* x   = (const float*)d_in[0];
  const float* wg1 = (const float*)d_in[1];
  const float* bg1 = (const float*)d_in[2];
  const float* wg2 = (const float*)d_in[3];
  const float* bg2 = (const float*)d_in[4];
  const float* w1  = (const float*)d_in[5];
  const float* b1  = (const float*)d_in[6];
  const float* w2  = (const float*)d_in[7];
  const float* b2  = (const float*)d_in[8];
  float* y = (float*)d_out;

  char* ws = (char*)d_ws;
  u16* xb   = (u16*)(ws);                 // 33,554,432 B
  u16* w1t  = (u16*)(ws + 33554432);      //  4,194,304 B
  u16* w2t  = (u16*)(ws + 37748736);      //  4,194,304 B
  char* M   = ws + 41943040;              // metadata block
  int*    cnt      = (int*)(M);                 // 32 B
  int*    offs     = (int*)(M + 64);            // 32 B
  int*    hist     = (int*)(M + 128);           // 2,048 B
  int*    cbase    = (int*)(M + 2304);          // 2,048 B
  int*    tok_list = (int*)(M + 4608);          // 135,168 B -> ends M+139,776
  int*    top_i    = (int*)(M + 139776);        // 65,536 B
  float2* top_g    = (float2*)(M + 205312);     // 131,072 B
  int*    pos1     = (int*)(M + 336384);        // 65,536 B
  int*    pos2     = (int*)(M + 401920);        // 65,536 B -> ends M+467,456
  u16* h_c = (u16*)(ws + 42467328);       // MAXP*256*2 = 17,301,504 B
  u16* o_c = (u16*)(ws + 59768832);       // MAXP*1024*2 = 69,206,016 B (total ~123 MiB)
  // p_buf [4][T][256] f32 = 67,108,864 B aliased onto o_c: dead before moe_out writes o_c
  float* p_buf = (float*)(ws + 59768832);

  // zero tok_list (pad slots -> token 0); everything else fully overwritten each call
  hipMemsetAsync(tok_list, 0, 135168, stream);
  transpose_cvt_kernel<<<dim3(32, 8, 8), 256, 0, stream>>>(w1, w1t, 1024, 256);
  transpose_cvt_kernel<<<dim3(8, 32, 8), 256, 0, stream>>>(w2, w2t, 256, 1024);
  gating_p1_kernel<<<dim3(256, 4), 256, 0, stream>>>(x, wg1, xb, p_buf);
  gating_p2_kernel<<<512, 256, 0, stream>>>(p_buf, bg1, wg2, bg2, top_i, top_g);
  hist_kernel<<<64, 256, 0, stream>>>(top_i, hist);
  scan_kernel<<<1, 64, 0, stream>>>(hist, cnt, offs, cbase);
  fill_kernel<<<64, 256, 0, stream>>>(top_i, cbase, tok_list, pos1, pos2);
  expert_h_kernel<<<dim3(128, 2, 8), 256, 0, stream>>>(xb, w1t, b1, tok_list, cnt, offs, h_c);
  moe_out_kernel <<<dim3(128, 8, 8), 256, 0, stream>>>(h_c, w2t, b2, cnt, offs, o_c);
  gather_kernel  <<<16384, 256, 0, stream>>>(o_c, pos1, pos2, top_g, y);
}

// Round 9
// 261.536 us; speedup vs baseline: 5.9580x; 5.9580x over previous
//
#include <hip/hip_runtime.h>

typedef unsigned short u16;
typedef __attribute__((ext_vector_type(8))) short bf16x8;
typedef __attribute__((ext_vector_type(4))) float f32x4;
typedef __attribute__((ext_vector_type(4))) u16 u16x4;
typedef __attribute__((ext_vector_type(2))) u16 u16x2;

#define T_TOK 16384
#define D_DIM 1024
#define NE 8
#define MAXP 33792   // max padded compact rows: 2*T + 8*128

__device__ __forceinline__ u16 f2bf(float f) {
  union { float f; unsigned int u; } c; c.f = f;
  unsigned int u = c.u;
  u += 0x7fffu + ((u >> 16) & 1u);   // round-to-nearest-even
  return (u16)(u >> 16);
}

__device__ __forceinline__ float bf2f(u16 v) {
  union { unsigned int u; float f; } c; c.u = ((unsigned int)v) << 16;
  return c.f;
}

__device__ __forceinline__ float gelu_exact(float u) {
  return 0.5f * u * (1.0f + erff(u * 0.70710678118654752f));
}

__device__ __forceinline__ void gld16(const void* g, void* l) {
  __builtin_amdgcn_global_load_lds(
      (const __attribute__((address_space(1))) unsigned int*)g,
      (__attribute__((address_space(3))) unsigned int*)l, 16, 0, 0);
}

// Stage a 128-row x 64-col bf16 tile (contiguous rows) into linear LDS [128][64].
__device__ __forceinline__ void stage_tile(u16* lds, const char* g0, size_t stride,
                                           int wid, int lane) {
  const char* g = g0 + (size_t)(wid * 8 + (lane >> 3)) * stride + (size_t)((lane & 7) * 16);
  char* l = (char*)lds + wid * 1024;   // wave-uniform LDS base; HW adds lane*16
  #pragma unroll
  for (int c = 0; c < 4; ++c)
    gld16(g + (size_t)(32 * c) * stride, l + c * 4096);
}

// One BK=64 step: 32 MFMA per wave, acc[4][4] (64x64 per wave, 2x2 waves = 128x128)
__device__ __forceinline__ void mma_step(const u16* As, const u16* Bs, f32x4 acc[4][4],
                                         int wm, int wn, int lane) {
  const int r = lane & 15, kq = (lane >> 4) * 8;
  #pragma unroll
  for (int ks = 0; ks < 2; ++ks) {
    const int col = ks * 32 + kq;
    bf16x8 a[4], b[4];
    #pragma unroll
    for (int mf = 0; mf < 4; ++mf)
      a[mf] = *(const bf16x8*)&As[(wm * 64 + mf * 16 + r) * 64 + col];
    #pragma unroll
    for (int nf = 0; nf < 4; ++nf)
      b[nf] = *(const bf16x8*)&Bs[(wn * 64 + nf * 16 + r) * 64 + col];
    #pragma unroll
    for (int mf = 0; mf < 4; ++mf)
      #pragma unroll
      for (int nf = 0; nf < 4; ++nf)
        acc[mf][nf] = __builtin_amdgcn_mfma_f32_16x16x32_bf16(a[mf], b[nf], acc[mf][nf], 0, 0, 0);
  }
}

// ---------------- tiled transpose+convert: in[e][R][C] f32 -> out[e][C][R] bf16 ----------------
__global__ __launch_bounds__(256) void transpose_cvt_kernel(const float* __restrict__ in,
                                                            u16* __restrict__ out,
                                                            int R, int C) {
  __shared__ u16 t[32][36];
  const int e = blockIdx.z;
  const int r0 = blockIdx.x * 32, c0 = blockIdx.y * 32;
  const int tid = threadIdx.x;
  {
    const int r = tid >> 3, cq = (tid & 7) * 4;
    float4 v = *(const float4*)(in + ((size_t)e * R + r0 + r) * C + c0 + cq);
    t[r][cq + 0] = f2bf(v.x); t[r][cq + 1] = f2bf(v.y);
    t[r][cq + 2] = f2bf(v.z); t[r][cq + 3] = f2bf(v.w);
  }
  __syncthreads();
  {
    const int c = tid >> 3, rq = (tid & 7) * 4;
    u16x4 o;
    o.x = t[rq + 0][c]; o.y = t[rq + 1][c]; o.z = t[rq + 2][c]; o.w = t[rq + 3][c];
    *(u16x4*)(out + ((size_t)e * C + c0 + c) * R + r0 + rq) = o;
  }
}

// ---------------- gating phase 1: partial GEMM1 over a K-quarter ----------------
// grid (256, 4): blockIdx.x = token block (64 tokens), blockIdx.y = K-quarter (256 K).
// 256 threads, BN=256 (full), BK=8 double-buffered. Thread (tm=tid>>5 in 0..7, tn=tid&31):
// 8 tokens (tm*8..+7) x 8 cols ({tn*4+j, 128+tn*4+j}) -> 64 FMA per 4 ds_read_b128
// (A-reads are 2-address wave-broadcast). Writes fp32 partials + its K-quarter of xb.
// NOTE: launch_bounds (256,2) — acc[8][8]=64 f32 + operands needs ~100 VGPR; the
// (256,4) cap at 64 VGPR spilled acc to scratch (R8: 6.9 GB HBM traffic, 11x slower).
__global__ __launch_bounds__(256, 2) void gating_p1_kernel(
    const float* __restrict__ x, const float* __restrict__ wg1,
    u16* __restrict__ xb, float* __restrict__ p_buf) {
  __shared__ float As[2][8][68];    // transposed x chunk [k][m], pad 68 keeps 16B align
  __shared__ float Bs[2][8 * 256];  // wg1 chunk [k][n], linear for global_load_lds
  const int tid = threadIdx.x;
  const int lane = tid & 63, w = tid >> 6;
  const int tn = tid & 31, tm = tid >> 5;
  const int t0 = blockIdx.x * 64;
  const int kq = blockIdx.y;
  const int kbeg = kq * 256;
  const int srow = tid >> 2, sc2 = (tid & 3) * 2;   // 64 rows x (4 thr x 2 k)

  float acc[8][8];
  #pragma unroll
  for (int i = 0; i < 8; ++i)
    #pragma unroll
    for (int j = 0; j < 8; ++j) acc[i][j] = 0.f;

  // ---- prologue: stage first tile into buffer 0 ----
  {
    const char* g = (const char*)wg1 + (size_t)(kbeg + w * 2) * 1024 + lane * 16;
    char* l = (char*)&Bs[0][0] + w * 2048;
    gld16(g, l);
    gld16(g + 1024, l + 1024);
  }
  {
    const float* src = x + (size_t)(t0 + srow) * 1024 + kbeg + sc2;
    float2 v = *(const float2*)src;
    As[0][sc2 + 0][srow] = v.x; As[0][sc2 + 1][srow] = v.y;
    u16x2 o; o.x = f2bf(v.x); o.y = f2bf(v.y);
    *(u16x2*)(xb + (size_t)(t0 + srow) * 1024 + kbeg + sc2) = o;
  }
  __syncthreads();

  int cur = 0;
  for (int k0 = kbeg; k0 < kbeg + 256; k0 += 8) {
    const bool has_next = (k0 + 8) < kbeg + 256;
    float2 xv;
    if (has_next) {
      const char* g = (const char*)wg1 + (size_t)(k0 + 8 + w * 2) * 1024 + lane * 16;
      char* l = (char*)&Bs[cur ^ 1][0] + w * 2048;
      gld16(g, l);
      gld16(g + 1024, l + 1024);
      xv = *(const float2*)(x + (size_t)(t0 + srow) * 1024 + k0 + 8 + sc2);
    }
    #pragma unroll
    for (int kk = 0; kk < 8; ++kk) {
      float4 a0 = *(const float4*)&As[cur][kk][tm * 8];
      float4 a1 = *(const float4*)&As[cur][kk][tm * 8 + 4];
      float4 b0 = *(const float4*)&Bs[cur][kk * 256 + tn * 4];
      float4 b1 = *(const float4*)&Bs[cur][kk * 256 + 128 + tn * 4];
      float av[8] = {a0.x, a0.y, a0.z, a0.w, a1.x, a1.y, a1.z, a1.w};
      float bv[8] = {b0.x, b0.y, b0.z, b0.w, b1.x, b1.y, b1.z, b1.w};
      #pragma unroll
      for (int i = 0; i < 8; ++i)
        #pragma unroll
        for (int j = 0; j < 8; ++j) acc[i][j] += av[i] * bv[j];
    }
    if (has_next) {
      As[cur ^ 1][sc2 + 0][srow] = xv.x; As[cur ^ 1][sc2 + 1][srow] = xv.y;
      u16x2 o; o.x = f2bf(xv.x); o.y = f2bf(xv.y);
      *(u16x2*)(xb + (size_t)(t0 + srow) * 1024 + k0 + 8 + sc2) = o;
    }
    __syncthreads();
    cur ^= 1;
  }

  // store partials: p_buf[kq][t][col], coalesced float4
  #pragma unroll
  for (int i = 0; i < 8; ++i) {
    const size_t t = t0 + tm * 8 + i;
    float* p = &p_buf[((size_t)kq * T_TOK + t) * 256];
    *(float4*)&p[tn * 4]       = make_float4(acc[i][0], acc[i][1], acc[i][2], acc[i][3]);
    *(float4*)&p[128 + tn * 4] = make_float4(acc[i][4], acc[i][5], acc[i][6], acc[i][7]);
  }
}

// ---------------- gating phase 2: combine 4 partials + gelu + GEMM2 + softmax + top2 ----------------
__global__ __launch_bounds__(256) void gating_p2_kernel(
    const float* __restrict__ p_buf, const float* __restrict__ bg1,
    const float* __restrict__ wg2, const float* __restrict__ bg2,
    int* __restrict__ top_i, float2* __restrict__ top_g) {
  const int tid = threadIdx.x;
  const int tn = tid & 31, tm = tid >> 5;
  const int t0 = blockIdx.x * 32;

  float bb[8];
  {
    float4 ba = *(const float4*)&bg1[tn * 4];
    float4 bc = *(const float4*)&bg1[128 + tn * 4];
    bb[0] = ba.x; bb[1] = ba.y; bb[2] = ba.z; bb[3] = ba.w;
    bb[4] = bc.x; bb[5] = bc.y; bb[6] = bc.z; bb[7] = bc.w;
  }

  // h values for this thread's 4 tokens x 8 cols
  float hv[4][8];
  #pragma unroll
  for (int i = 0; i < 4; ++i) {
    const size_t t = t0 + tm * 4 + i;
    float s[8];
    #pragma unroll
    for (int j = 0; j < 8; ++j) s[j] = 0.f;
    #pragma unroll
    for (int q = 0; q < 4; ++q) {
      const float* p = &p_buf[((size_t)q * T_TOK + t) * 256];
      float4 a0 = *(const float4*)&p[tn * 4];
      float4 a1 = *(const float4*)&p[128 + tn * 4];
      s[0] += a0.x; s[1] += a0.y; s[2] += a0.z; s[3] += a0.w;
      s[4] += a1.x; s[5] += a1.y; s[6] += a1.z; s[7] += a1.w;
    }
    #pragma unroll
    for (int j = 0; j < 8; ++j) hv[i][j] = gelu_exact(s[j] + bb[j]);
  }

  float part[4][8];
  #pragma unroll
  for (int i = 0; i < 4; ++i)
    #pragma unroll
    for (int e = 0; e < 8; ++e) part[i][e] = 0.f;
  #pragma unroll
  for (int j = 0; j < 8; ++j) {
    const int col = (j < 4) ? (tn * 4 + j) : (128 + tn * 4 + (j - 4));
    float4 wa = *(const float4*)&wg2[col * 8];
    float4 wb = *(const float4*)&wg2[col * 8 + 4];
    float we[8] = {wa.x, wa.y, wa.z, wa.w, wb.x, wb.y, wb.z, wb.w};
    #pragma unroll
    for (int i = 0; i < 4; ++i)
      #pragma unroll
      for (int e = 0; e < 8; ++e) part[i][e] += hv[i][j] * we[e];
  }
  #pragma unroll
  for (int mask = 1; mask < 32; mask <<= 1)
    #pragma unroll
    for (int i = 0; i < 4; ++i)
      #pragma unroll
      for (int e = 0; e < 8; ++e) part[i][e] += __shfl_xor(part[i][e], mask);

  if (tn < 4) {
    float lg[8];
    #pragma unroll
    for (int i = 0; i < 4; ++i)
      if (tn == i) {
        #pragma unroll
        for (int e = 0; e < 8; ++e) lg[e] = part[i][e];
      }
    #pragma unroll
    for (int e = 0; e < 8; ++e) lg[e] += bg2[e];
    float m = lg[0];
    #pragma unroll
    for (int e = 1; e < 8; ++e) m = fmaxf(m, lg[e]);
    float ex[8], s = 0.f;
    #pragma unroll
    for (int e = 0; e < 8; ++e) { ex[e] = expf(lg[e] - m); s += ex[e]; }
    int i1 = 0;
    #pragma unroll
    for (int e = 1; e < 8; ++e) if (lg[e] > lg[i1]) i1 = e;   // strict >: lowest idx on tie
    int i2 = (i1 == 0) ? 1 : 0;
    #pragma unroll
    for (int e = 0; e < 8; ++e) if (e != i1 && lg[e] > lg[i2]) i2 = e;
    float inv = 1.f / s;
    const int t = t0 + tm * 4 + tn;
    top_i[t] = i1 | (i2 << 8);
    top_g[t] = make_float2(ex[i1] * inv, ex[i2] * inv);
  }
}

// ---------------- hist: per-256-token-chunk expert histogram (LDS atomics only) ----------------
__global__ __launch_bounds__(256) void hist_kernel(const int* __restrict__ top_i,
                                                   int* __restrict__ hist) {
  __shared__ int h[NE];
  const int tid = threadIdx.x;
  if (tid < NE) h[tid] = 0;
  __syncthreads();
  const int ti = top_i[blockIdx.x * 256 + tid];
  atomicAdd(&h[ti & 255], 1);
  atomicAdd(&h[ti >> 8], 1);
  __syncthreads();
  if (tid < NE) hist[blockIdx.x * NE + tid] = h[tid];
}

// ---------------- scan: totals, padded offsets, per-chunk bases (single block) ----------------
__global__ __launch_bounds__(64) void scan_kernel(const int* __restrict__ hist,
                                                  int* __restrict__ cnt,
                                                  int* __restrict__ offs,
                                                  int* __restrict__ cbase) {
  __shared__ int tot[NE], off_s[NE];
  const int tid = threadIdx.x;
  if (tid < NE) {
    int s = 0;
    for (int c = 0; c < 64; ++c) s += hist[c * NE + tid];
    tot[tid] = s; cnt[tid] = s;
  }
  __syncthreads();
  if (tid == 0) {
    int o = 0;
    #pragma unroll
    for (int e = 0; e < NE; ++e) { off_s[e] = o; o += (tot[e] + 127) & ~127; }
  }
  __syncthreads();
  if (tid < NE) {
    offs[tid] = off_s[tid];
    int r = off_s[tid];
    for (int c = 0; c < 64; ++c) { cbase[c * NE + tid] = r; r += hist[c * NE + tid]; }
  }
}

// ---------------- fill: scatter tokens into per-expert compact lists (LDS atomics) ----------------
__global__ __launch_bounds__(256) void fill_kernel(
    const int* __restrict__ top_i, const int* __restrict__ cbase,
    int* __restrict__ tok_list, int* __restrict__ pos1, int* __restrict__ pos2) {
  __shared__ int lcnt[NE];
  const int tid = threadIdx.x;
  if (tid < NE) lcnt[tid] = 0;
  __syncthreads();
  const int t = blockIdx.x * 256 + tid;
  const int ti = top_i[t];
  const int i1 = ti & 255, i2 = ti >> 8;
  const int r1 = atomicAdd(&lcnt[i1], 1);
  const int r2 = atomicAdd(&lcnt[i2], 1);
  const int p1 = cbase[blockIdx.x * NE + i1] + r1;
  const int p2 = cbase[blockIdx.x * NE + i2] + r2;
  tok_list[p1] = t; tok_list[p2] = t;
  pos1[t] = p1; pos2[t] = p2;
}

// ---------------- pass A (compact): h[p][h] = gelu(x[tok[p]] @ W1e + b1e), bf16 ----------------
__global__ __launch_bounds__(256) void expert_h_kernel(
    const u16* __restrict__ xb, const u16* __restrict__ w1t,
    const float* __restrict__ b1, const int* __restrict__ tok_list,
    const int* __restrict__ cnt, const int* __restrict__ offs,
    u16* __restrict__ h_c) {
  __shared__ u16 As[128 * 64];
  __shared__ u16 Bs[128 * 64];
  __shared__ float b1_s[128];
  const int e = blockIdx.z;
  const int nblk = (cnt[e] + 127) >> 7;
  if ((int)blockIdx.x >= nblk) return;
  const int tid = threadIdx.x, lane = tid & 63, wid = tid >> 6;
  const int base = offs[e] + blockIdx.x * 128;
  const int n0 = blockIdx.y * 128;
  const int wm = wid >> 1, wn = wid & 1;

  if (tid < 128) b1_s[tid] = b1[e * 256 + n0 + tid];

  // token ids for this wave's staged rows (hoisted out of the K loop)
  int tk[4];
  {
    const int r0 = wid * 8 + (lane >> 3);
    #pragma unroll
    for (int c = 0; c < 4; ++c) tk[c] = tok_list[base + r0 + 32 * c];
  }

  f32x4 acc[4][4];
  #pragma unroll
  for (int i = 0; i < 4; ++i)
    #pragma unroll
    for (int j = 0; j < 4; ++j) acc[i][j] = (f32x4){0.f, 0.f, 0.f, 0.f};

  const char* Bb = (const char*)w1t + ((size_t)e * 256 + n0) * 2048;
  const int cb = (lane & 7) * 16;
  for (int kt = 0; kt < 16; ++kt) {
    __syncthreads();
    {   // gather-stage A: per-lane global row = tok_list row
      char* l = (char*)As + wid * 1024;
      #pragma unroll
      for (int c = 0; c < 4; ++c)
        gld16((const char*)xb + (size_t)tk[c] * 2048 + kt * 128 + cb, l + c * 4096);
    }
    stage_tile(Bs, Bb + kt * 128, 2048, wid, lane);
    __syncthreads();
    mma_step(As, Bs, acc, wm, wn, lane);
  }

  #pragma unroll
  for (int mf = 0; mf < 4; ++mf)
    #pragma unroll
    for (int rr = 0; rr < 4; ++rr) {
      const int lt = wm * 64 + mf * 16 + ((lane >> 4) << 2) + rr;
      #pragma unroll
      for (int nf = 0; nf < 4; ++nf) {
        const int ln = wn * 64 + nf * 16 + (lane & 15);
        float u = acc[mf][nf][rr] + b1_s[ln];
        h_c[(size_t)(base + lt) * 256 + n0 + ln] = f2bf(gelu_exact(u));
      }
    }
}

// ---------------- pass B (compact): o[p][d] = h[p] @ W2e + b2e, bf16 ----------------
__global__ __launch_bounds__(256) void moe_out_kernel(
    const u16* __restrict__ h_c, const u16* __restrict__ w2t,
    const float* __restrict__ b2, const int* __restrict__ cnt,
    const int* __restrict__ offs, u16* __restrict__ o_c) {
  __shared__ u16 As[128 * 64];
  __shared__ u16 Bs[128 * 64];
  __shared__ float b2_s[128];
  const int e = blockIdx.z;
  const int nblk = (cnt[e] + 127) >> 7;
  if ((int)blockIdx.x >= nblk) return;
  const int tid = threadIdx.x, lane = tid & 63, wid = tid >> 6;
  const int base = offs[e] + blockIdx.x * 128;
  const int n0 = blockIdx.y * 128;
  const int wm = wid >> 1, wn = wid & 1;

  if (tid < 128) b2_s[tid] = b2[(size_t)e * 1024 + n0 + tid];

  f32x4 acc[4][4];
  #pragma unroll
  for (int i = 0; i < 4; ++i)
    #pragma unroll
    for (int j = 0; j < 4; ++j) acc[i][j] = (f32x4){0.f, 0.f, 0.f, 0.f};

  const char* Ab = (const char*)h_c + (size_t)base * 512;
  const char* Bb = (const char*)w2t + ((size_t)e * D_DIM + n0) * 512;
  #pragma unroll 1
  for (int kt = 0; kt < 4; ++kt) {
    __syncthreads();
    stage_tile(As, Ab + kt * 128, 512, wid, lane);
    stage_tile(Bs, Bb + kt * 128, 512, wid, lane);
    __syncthreads();
    mma_step(As, Bs, acc, wm, wn, lane);
  }

  #pragma unroll
  for (int mf = 0; mf < 4; ++mf)
    #pragma unroll
    for (int rr = 0; rr < 4; ++rr) {
      const int lt = wm * 64 + mf * 16 + ((lane >> 4) << 2) + rr;
      #pragma unroll
      for (int nf = 0; nf < 4; ++nf) {
        const int ln = wn * 64 + nf * 16 + (lane & 15);
        o_c[(size_t)(base + lt) * 1024 + n0 + ln] = f2bf(acc[mf][nf][rr] + b2_s[ln]);
      }
    }
}

// ---------------- gather: y[t] = g1*o[p1] + g2*o[p2] ----------------
__global__ __launch_bounds__(256) void gather_kernel(
    const u16* __restrict__ o_c, const int* __restrict__ pos1,
    const int* __restrict__ pos2, const float2* __restrict__ top_g,
    float* __restrict__ y) {
  const int t = blockIdx.x;
  const int p1 = pos1[t], p2 = pos2[t];
  const float2 g = top_g[t];
  const int c = threadIdx.x * 4;
  u16x4 a = *(const u16x4*)&o_c[(size_t)p1 * 1024 + c];
  u16x4 b = *(const u16x4*)&o_c[(size_t)p2 * 1024 + c];
  float4 o;
  o.x = g.x * bf2f(a.x) + g.y * bf2f(b.x);
  o.y = g.x * bf2f(a.y) + g.y * bf2f(b.y);
  o.z = g.x * bf2f(a.z) + g.y * bf2f(b.z);
  o.w = g.x * bf2f(a.w) + g.y * bf2f(b.w);
  *(float4*)&y[(size_t)t * 1024 + c] = o;
}

extern "C" void kernel_launch(void* const* d_in, const int* in_sizes, int n_in,
                              void* d_out, int out_size, void* d_ws, size_t ws_size,
                              hipStream_t stream) {
  (void)in_sizes; (void)n_in; (void)out_size; (void)ws_size;
  const float* x   = (const float*)d_in[0];
  const float* wg1 = (const float*)d_in[1];
  const float* bg1 = (const float*)d_in[2];
  const float* wg2 = (const float*)d_in[3];
  const float* bg2 = (const float*)d_in[4];
  const float* w1  = (const float*)d_in[5];
  const float* b1  = (const float*)d_in[6];
  const float* w2  = (const float*)d_in[7];
  const float* b2  = (const float*)d_in[8];
  float* y = (float*)d_out;

  char* ws = (char*)d_ws;
  u16* xb   = (u16*)(ws);                 // 33,554,432 B
  u16* w1t  = (u16*)(ws + 33554432);      //  4,194,304 B
  u16* w2t  = (u16*)(ws + 37748736);      //  4,194,304 B
  char* M   = ws + 41943040;              // metadata block
  int*    cnt      = (int*)(M);                 // 32 B
  int*    offs     = (int*)(M + 64);            // 32 B
  int*    hist     = (int*)(M + 128);           // 2,048 B
  int*    cbase    = (int*)(M + 2304);          // 2,048 B
  int*    tok_list = (int*)(M + 4608);          // 135,168 B -> ends M+139,776
  int*    top_i    = (int*)(M + 139776);        // 65,536 B
  float2* top_g    = (float2*)(M + 205312);     // 131,072 B
  int*    pos1     = (int*)(M + 336384);        // 65,536 B
  int*    pos2     = (int*)(M + 401920);        // 65,536 B -> ends M+467,456
  u16* h_c = (u16*)(ws + 42467328);       // MAXP*256*2 = 17,301,504 B
  u16* o_c = (u16*)(ws + 59768832);       // MAXP*1024*2 = 69,206,016 B (total ~123 MiB)
  // p_buf [4][T][256] f32 = 67,108,864 B aliased onto o_c: dead before moe_out writes o_c
  float* p_buf = (float*)(ws + 59768832);

  // zero tok_list (pad slots -> token 0); everything else fully overwritten each call
  hipMemsetAsync(tok_list, 0, 135168, stream);
  transpose_cvt_kernel<<<dim3(32, 8, 8), 256, 0, stream>>>(w1, w1t, 1024, 256);
  transpose_cvt_kernel<<<dim3(8, 32, 8), 256, 0, stream>>>(w2, w2t, 256, 1024);
  gating_p1_kernel<<<dim3(256, 4), 256, 0, stream>>>(x, wg1, xb, p_buf);
  gating_p2_kernel<<<512, 256, 0, stream>>>(p_buf, bg1, wg2, bg2, top_i, top_g);
  hist_kernel<<<64, 256, 0, stream>>>(top_i, hist);
  scan_kernel<<<1, 64, 0, stream>>>(hist, cnt, offs, cbase);
  fill_kernel<<<64, 256, 0, stream>>>(top_i, cbase, tok_list, pos1, pos2);
  expert_h_kernel<<<dim3(128, 2, 8), 256, 0, stream>>>(xb, w1t, b1, tok_list, cnt, offs, h_c);
  moe_out_kernel <<<dim3(128, 8, 8), 256, 0, stream>>>(h_c, w2t, b2, cnt, offs, o_c);
  gather_kernel  <<<16384, 256, 0, stream>>>(o_c, pos1, pos2, top_g, y);
}